// Round 1
// baseline (393.043 us; speedup 1.0000x reference)
//
#include <hip/hip_runtime.h>
#include <hip/hip_bf16.h>
#include <math.h>

#define HID 128
#define NH 8
#define DH 16

// ---------------------------------------------------------------------------
// Kernel 1: CSR row pointers via binary search (row is sorted).
// ---------------------------------------------------------------------------
__global__ void rowptr_kernel(const int* __restrict__ row, int* __restrict__ row_ptr,
                              int N_, int E_) {
    int i = blockIdx.x * blockDim.x + threadIdx.x;
    if (i > N_) return;
    int lo = 0, hi = E_;
    while (lo < hi) {
        int mid = (lo + hi) >> 1;
        if (row[mid] < i) lo = mid + 1; else hi = mid;
    }
    row_ptr[i] = lo;
}

// ---------------------------------------------------------------------------
// Kernel 2: fused QKV projection. C[m,o] = sum_k h[m,k]*W[o,k] + b[o],
// stored with head-major column permutation p = (o&7)*16 + (o>>3) so that the
// edge kernel can read 4 consecutive channels of one head per lane.
// Tile: 64 rows x 64 cols, 256 threads, 4x4 per thread, K=128 staged in LDS.
// ---------------------------------------------------------------------------
#define LDT 132  // padded LDS row stride (floats); 132*4 = 528 B, 16B-aligned rows

__global__ __launch_bounds__(256, 2)
void qkv_gemm_kernel(const float* __restrict__ h, int M,
                     const float* __restrict__ Wq, const float* __restrict__ Wk,
                     const float* __restrict__ Wv,
                     const float* __restrict__ bq, const float* __restrict__ bk,
                     const float* __restrict__ bv,
                     float* __restrict__ qo, float* __restrict__ ko,
                     float* __restrict__ vo) {
    __shared__ float As[64][LDT];
    __shared__ float Bs[64][LDT];
    int tid = threadIdx.x;
    int by  = blockIdx.y;            // 0..5
    int wsel = by >> 1;              // 0=q,1=k,2=v
    int n0   = (by & 1) * 64;        // column offset inside the 128-wide weight
    const float* W    = (wsel == 0) ? Wq : (wsel == 1) ? Wk : Wv;
    const float* bias = (wsel == 0) ? bq : (wsel == 1) ? bk : bv;
    float* out        = (wsel == 0) ? qo : (wsel == 1) ? ko : vo;

    int m0 = blockIdx.x * 64;

    // Stage A tile (64x128) and B tile (64 weight rows x 128) as float4, coalesced.
    #pragma unroll
    for (int r = 0; r < 8; ++r) {
        int f  = r * 256 + tid;
        int mm = f >> 5;             // 0..63
        int kq = f & 31;             // 0..31 (float4 index)
        int mg = m0 + mm;
        float4 val = (mg < M) ? *(const float4*)&h[(size_t)mg * HID + kq * 4]
                              : make_float4(0.f, 0.f, 0.f, 0.f);
        *(float4*)&As[mm][kq * 4] = val;
    }
    #pragma unroll
    for (int r = 0; r < 8; ++r) {
        int f  = r * 256 + tid;
        int oo = f >> 5;
        int kq = f & 31;
        float4 val = *(const float4*)&W[(size_t)(n0 + oo) * HID + kq * 4];
        *(float4*)&Bs[oo][kq * 4] = val;
    }
    __syncthreads();

    int tx = tid & 15, ty = tid >> 4;
    float acc[4][4] = {};
    #pragma unroll 8
    for (int kq = 0; kq < 32; ++kq) {
        float4 a4[4], b4[4];
        #pragma unroll
        for (int i = 0; i < 4; ++i) a4[i] = *(float4*)&As[ty * 4 + i][kq * 4];
        #pragma unroll
        for (int j = 0; j < 4; ++j) b4[j] = *(float4*)&Bs[tx * 4 + j][kq * 4];
        #pragma unroll
        for (int i = 0; i < 4; ++i)
            #pragma unroll
            for (int j = 0; j < 4; ++j)
                acc[i][j] += a4[i].x * b4[j].x + a4[i].y * b4[j].y +
                             a4[i].z * b4[j].z + a4[i].w * b4[j].w;
    }

    // Epilogue: bias + head-major permuted store.
    #pragma unroll
    for (int i = 0; i < 4; ++i) {
        int mg = m0 + ty * 4 + i;
        if (mg >= M) continue;
        #pragma unroll
        for (int j = 0; j < 4; ++j) {
            int o = n0 + tx * 4 + j;                  // original projection column
            float val = acc[i][j] + bias[o];
            int p = (o & 7) * 16 + (o >> 3);          // head-major slot
            out[(size_t)mg * HID + p] = val;
        }
    }
}

// ---------------------------------------------------------------------------
// Kernel 3: fused SDDMM + online segment-softmax + SPMM.
// One wave per node; lane halves (32+32) process 2 edges per iteration.
// Lane sl (0..31) owns head-major channels 4sl..4sl+3 (all of head sl>>2).
// Output written back in the reference channel layout (c = d*8 + head).
// ---------------------------------------------------------------------------
__global__ __launch_bounds__(256)
void edge_attn_kernel(const int* __restrict__ row_ptr, const int* __restrict__ col,
                      const float* __restrict__ q, const float* __restrict__ k,
                      const float* __restrict__ v, float* __restrict__ out, int N_) {
    int wave = threadIdx.x >> 6;
    int lane = threadIdx.x & 63;
    int node = blockIdx.x * 4 + wave;
    if (node >= N_) return;
    int sl   = lane & 31;
    int half = lane >> 5;

    float4 q4 = *(const float4*)&q[(size_t)node * HID + sl * 4];
    int e0 = row_ptr[node];
    int e1 = row_ptr[node + 1];

    float m = -INFINITY, z = 0.f;
    float4 acc = make_float4(0.f, 0.f, 0.f, 0.f);

    for (int eb = e0; eb < e1; eb += 2) {
        int my_e   = eb + half;
        bool valid = (my_e < e1);
        int cnode  = valid ? col[my_e] : col[eb];
        float4 k4 = *(const float4*)&k[(size_t)cnode * HID + sl * 4];
        float4 v4 = *(const float4*)&v[(size_t)cnode * HID + sl * 4];
        float p = q4.x * k4.x + q4.y * k4.y + q4.z * k4.z + q4.w * k4.w;
        p += __shfl_xor(p, 1);
        p += __shfl_xor(p, 2);
        float s = valid ? p * 0.25f : -INFINITY;   // 1/sqrt(DH) = 0.25
        float mnew = fmaxf(m, s);
        if (mnew > -INFINITY) {
            float alpha = __expf(m - mnew);
            float w     = __expf(s - mnew);
            z = z * alpha + w;
            acc.x = acc.x * alpha + w * v4.x;
            acc.y = acc.y * alpha + w * v4.y;
            acc.z = acc.z * alpha + w * v4.z;
            acc.w = acc.w * alpha + w * v4.w;
            m = mnew;
        }
    }

    // Merge the two 32-lane halves (each lane pairs with lane^32, same sl).
    float m2 = __shfl_xor(m, 32);
    float z2 = __shfl_xor(z, 32);
    float ax = __shfl_xor(acc.x, 32);
    float ay = __shfl_xor(acc.y, 32);
    float az = __shfl_xor(acc.z, 32);
    float aw = __shfl_xor(acc.w, 32);
    float mm = fmaxf(m, m2);
    if (mm > -INFINITY) {
        float a1 = __expf(m - mm);
        float a2 = __expf(m2 - mm);
        z = z * a1 + z2 * a2;
        acc.x = acc.x * a1 + ax * a2;
        acc.y = acc.y * a1 + ay * a2;
        acc.z = acc.z * a1 + az * a2;
        acc.w = acc.w * a1 + aw * a2;
    }

    if (half == 0) {
        float inv = (z > 0.f) ? 1.0f / z : 0.f;
        float r[4] = {acc.x * inv, acc.y * inv, acc.z * inv, acc.w * inv};
        #pragma unroll
        for (int jj = 0; jj < 4; ++jj) {
            int cp = sl * 4 + jj;          // head-major channel
            int d  = cp & 15;
            int hd = cp >> 4;
            out[(size_t)node * HID + d * 8 + hd] = r[jj];   // reference layout
        }
    }
}

// ---------------------------------------------------------------------------
// Kernel 4: output projection. Same tile structure as kernel 2, no permute,
// vectorized float4 stores.
// ---------------------------------------------------------------------------
__global__ __launch_bounds__(256, 2)
void out_gemm_kernel(const float* __restrict__ A, int M,
                     const float* __restrict__ W, const float* __restrict__ bias,
                     float* __restrict__ C) {
    __shared__ float As[64][LDT];
    __shared__ float Bs[64][LDT];
    int tid = threadIdx.x;
    int n0  = blockIdx.y * 64;
    int m0  = blockIdx.x * 64;

    #pragma unroll
    for (int r = 0; r < 8; ++r) {
        int f  = r * 256 + tid;
        int mm = f >> 5;
        int kq = f & 31;
        int mg = m0 + mm;
        float4 val = (mg < M) ? *(const float4*)&A[(size_t)mg * HID + kq * 4]
                              : make_float4(0.f, 0.f, 0.f, 0.f);
        *(float4*)&As[mm][kq * 4] = val;
    }
    #pragma unroll
    for (int r = 0; r < 8; ++r) {
        int f  = r * 256 + tid;
        int oo = f >> 5;
        int kq = f & 31;
        float4 val = *(const float4*)&W[(size_t)(n0 + oo) * HID + kq * 4];
        *(float4*)&Bs[oo][kq * 4] = val;
    }
    __syncthreads();

    int tx = tid & 15, ty = tid >> 4;
    float acc[4][4] = {};
    #pragma unroll 8
    for (int kq = 0; kq < 32; ++kq) {
        float4 a4[4], b4[4];
        #pragma unroll
        for (int i = 0; i < 4; ++i) a4[i] = *(float4*)&As[ty * 4 + i][kq * 4];
        #pragma unroll
        for (int j = 0; j < 4; ++j) b4[j] = *(float4*)&Bs[tx * 4 + j][kq * 4];
        #pragma unroll
        for (int i = 0; i < 4; ++i)
            #pragma unroll
            for (int j = 0; j < 4; ++j)
                acc[i][j] += a4[i].x * b4[j].x + a4[i].y * b4[j].y +
                             a4[i].z * b4[j].z + a4[i].w * b4[j].w;
    }

    #pragma unroll
    for (int i = 0; i < 4; ++i) {
        int mg = m0 + ty * 4 + i;
        if (mg >= M) continue;
        int o = n0 + tx * 4;
        float4 val = make_float4(acc[i][0] + bias[o + 0], acc[i][1] + bias[o + 1],
                                 acc[i][2] + bias[o + 2], acc[i][3] + bias[o + 3]);
        *(float4*)&C[(size_t)mg * HID + o] = val;
    }
}

// ---------------------------------------------------------------------------
extern "C" void kernel_launch(void* const* d_in, const int* in_sizes, int n_in,
                              void* d_out, int out_size, void* d_ws, size_t ws_size,
                              hipStream_t stream) {
    const float* h  = (const float*)d_in[0];
    const int* row  = (const int*)d_in[1];
    const int* col  = (const int*)d_in[2];
    const float* Wq = (const float*)d_in[3];
    const float* bq = (const float*)d_in[4];
    const float* Wk = (const float*)d_in[5];
    const float* bk = (const float*)d_in[6];
    const float* Wv = (const float*)d_in[7];
    const float* bv = (const float*)d_in[8];
    const float* Wo = (const float*)d_in[9];
    const float* bo = (const float*)d_in[10];
    float* out = (float*)d_out;

    int N_ = in_sizes[0] / HID;   // 50000
    int E_ = in_sizes[1];         // 800000

    char* ws = (char*)d_ws;
    size_t off = 0;
    auto alloc = [&](size_t bytes) {
        void* p = (void*)(ws + off);
        off = (off + bytes + 255) & ~(size_t)255;
        return p;
    };
    int*   row_ptr = (int*)  alloc((size_t)(N_ + 1) * sizeof(int));
    float* qb      = (float*)alloc((size_t)N_ * HID * sizeof(float));
    float* kb      = (float*)alloc((size_t)N_ * HID * sizeof(float));
    float* vb      = (float*)alloc((size_t)N_ * HID * sizeof(float));
    float* ob      = (float*)alloc((size_t)N_ * HID * sizeof(float));
    (void)ws_size;

    rowptr_kernel<<<(N_ + 256) / 256, 256, 0, stream>>>(row, row_ptr, N_, E_);
    qkv_gemm_kernel<<<dim3((N_ + 63) / 64, 6), 256, 0, stream>>>(
        h, N_, Wq, Wk, Wv, bq, bk, bv, qb, kb, vb);
    edge_attn_kernel<<<(N_ + 3) / 4, 256, 0, stream>>>(row_ptr, col, qb, kb, vb, ob, N_);
    out_gemm_kernel<<<dim3((N_ + 63) / 64, 2), 256, 0, stream>>>(ob, N_, Wo, bo, out);
}

// Round 2
// 304.963 us; speedup vs baseline: 1.2888x; 1.2888x over previous
//
#include <hip/hip_runtime.h>
#include <hip/hip_bf16.h>
#include <math.h>

#define HID 128
#define NH 8
#define DH 16

typedef __bf16 bf16x8 __attribute__((ext_vector_type(8)));
typedef float  f32x4  __attribute__((ext_vector_type(4)));

// ---------------------------------------------------------------------------
// Kernel 1: CSR row pointers via binary search (row is sorted).
// ---------------------------------------------------------------------------
__global__ void rowptr_kernel(const int* __restrict__ row, int* __restrict__ row_ptr,
                              int N_, int E_) {
    int i = blockIdx.x * blockDim.x + threadIdx.x;
    if (i > N_) return;
    int lo = 0, hi = E_;
    while (lo < hi) {
        int mid = (lo + hi) >> 1;
        if (row[mid] < i) lo = mid + 1; else hi = mid;
    }
    row_ptr[i] = lo;
}

// ---------------------------------------------------------------------------
// Kernel 2: split W (q,k,v,o) into bf16 hi/lo pairs; build fused bias384 in
// head-major permuted order.  65536 elements -> trivial.
// ---------------------------------------------------------------------------
__global__ void wsplit_kernel(const float* __restrict__ Wq, const float* __restrict__ Wk,
                              const float* __restrict__ Wv, const float* __restrict__ Wo,
                              const float* __restrict__ bq, const float* __restrict__ bk,
                              const float* __restrict__ bv,
                              __bf16* __restrict__ Whi, __bf16* __restrict__ Wlo,
                              float* __restrict__ bias384) {
    int idx = blockIdx.x * blockDim.x + threadIdx.x;
    if (idx < 4 * 16384) {
        int j = idx >> 14;
        int rem = idx & 16383;
        const float* W = (j == 0) ? Wq : (j == 1) ? Wk : (j == 2) ? Wv : Wo;
        float x = W[rem];
        __bf16 hv = (__bf16)x;
        float lo = x - (float)hv;
        Whi[idx] = hv;
        Wlo[idx] = (__bf16)lo;
    }
    if (idx < 384) {
        int j = idx >> 7;
        int pcol = idx & 127;                       // head-major col within proj
        int o = ((pcol & 15) << 3) | (pcol >> 4);   // original W row
        const float* b = (j == 0) ? bq : (j == 1) ? bk : bv;
        bias384[idx] = b[o];
    }
}

// ---------------------------------------------------------------------------
// Kernel 3: fused QKV projection via MFMA (bf16 hi/lo split = fp32 accuracy).
// Block: 256 thr = 4 waves; 64 rows/block shared by all waves; wave w owns
// global cols [w*96, w*96+96) of the fused 384-wide output (q|k|v head-major).
// B-fragment W row chosen via inverse head-major permutation so stores are
// contiguous.  out[m, p] written to qkv[m*384 + p], fp32.
// ---------------------------------------------------------------------------
__global__ __launch_bounds__(256)
void qkv_mfma_kernel(const float* __restrict__ h, int M,
                     const __bf16* __restrict__ Whi, const __bf16* __restrict__ Wlo,
                     const float* __restrict__ bias384, float* __restrict__ qkv) {
    int tid  = threadIdx.x;
    int wv   = tid >> 6;
    int lane = tid & 63;
    int r    = lane & 15;      // MFMA row (A) / col (B,C) index
    int kg   = lane >> 4;      // k-group (0..3), 8 elems each
    int m0   = blockIdx.x * 64;
    int colbase = wv * 96;

    f32x4 acc[6][4];
    #pragma unroll
    for (int cf = 0; cf < 6; ++cf)
        #pragma unroll
        for (int rf = 0; rf < 4; ++rf)
            acc[cf][rf] = (f32x4){0.f, 0.f, 0.f, 0.f};

    // per-lane W row element-offset for each col-fragment
    int wrow[6];
    #pragma unroll
    for (int cf = 0; cf < 6; ++cf) {
        int col  = colbase + cf * 16 + r;          // fused head-major col
        int j    = col >> 7;
        int pcol = col & 127;
        int o    = ((pcol & 15) << 3) | (pcol >> 4);
        wrow[cf] = (j * 128 + o) * 128;
    }

    #pragma unroll
    for (int t = 0; t < 4; ++t) {
        int k0 = t * 32 + kg * 8;
        bf16x8 Ahi[4], Alo[4];
        #pragma unroll
        for (int rf = 0; rf < 4; ++rf) {
            int mg = m0 + rf * 16 + r;
            if (mg > M - 1) mg = M - 1;
            const float* src = &h[(size_t)mg * HID + k0];
            float4 x0 = *(const float4*)src;
            float4 x1 = *(const float4*)(src + 4);
            float xs[8] = {x0.x, x0.y, x0.z, x0.w, x1.x, x1.y, x1.z, x1.w};
            #pragma unroll
            for (int e = 0; e < 8; ++e) {
                __bf16 hv = (__bf16)xs[e];
                Ahi[rf][e] = hv;
                Alo[rf][e] = (__bf16)(xs[e] - (float)hv);
            }
        }
        #pragma unroll
        for (int cf = 0; cf < 6; ++cf) {
            bf16x8 bh = *(const bf16x8*)&Whi[wrow[cf] + k0];
            bf16x8 bl = *(const bf16x8*)&Wlo[wrow[cf] + k0];
            #pragma unroll
            for (int rf = 0; rf < 4; ++rf) {
                acc[cf][rf] = __builtin_amdgcn_mfma_f32_16x16x32_bf16(Ahi[rf], bh, acc[cf][rf], 0, 0, 0);
                acc[cf][rf] = __builtin_amdgcn_mfma_f32_16x16x32_bf16(Alo[rf], bh, acc[cf][rf], 0, 0, 0);
                acc[cf][rf] = __builtin_amdgcn_mfma_f32_16x16x32_bf16(Ahi[rf], bl, acc[cf][rf], 0, 0, 0);
            }
        }
    }

    // epilogue: C layout col = lane&15, row = (lane>>4)*4 + e  [m89-verified]
    int orow = (lane >> 4) * 4;
    #pragma unroll
    for (int cf = 0; cf < 6; ++cf) {
        int col = colbase + cf * 16 + r;
        float b = bias384[col];
        #pragma unroll
        for (int rf = 0; rf < 4; ++rf) {
            #pragma unroll
            for (int e = 0; e < 4; ++e) {
                int mg = m0 + rf * 16 + orow + e;
                if (mg < M) qkv[(size_t)mg * 384 + col] = acc[cf][rf][e] + b;
            }
        }
    }
}

// ---------------------------------------------------------------------------
// Kernel 4: fused SDDMM + online segment-softmax + SPMM.
// One wave per node; lane halves (32+32) process 2 edges per iteration.
// Lane sl (0..31) owns head-major channels 4sl..4sl+3 (one head per 4 lanes).
// q/k/v live in the fused qkv buffer (row stride 384 floats).
// Output written in the reference channel layout (c = d*8 + head).
// ---------------------------------------------------------------------------
__global__ __launch_bounds__(256)
void edge_attn_kernel(const int* __restrict__ row_ptr, const int* __restrict__ col,
                      const float* __restrict__ qkv, float* __restrict__ out, int N_) {
    int wave = threadIdx.x >> 6;
    int lane = threadIdx.x & 63;
    int node = blockIdx.x * 4 + wave;
    if (node >= N_) return;
    int sl   = lane & 31;
    int half = lane >> 5;

    float4 q4 = *(const float4*)&qkv[(size_t)node * 384 + sl * 4];
    int e0 = row_ptr[node];
    int e1 = row_ptr[node + 1];

    float m = -INFINITY, z = 0.f;
    float4 acc = make_float4(0.f, 0.f, 0.f, 0.f);

    for (int eb = e0; eb < e1; eb += 2) {
        int my_e   = eb + half;
        bool valid = (my_e < e1);
        int cnode  = valid ? col[my_e] : col[eb];
        const float* kv = &qkv[(size_t)cnode * 384];
        float4 k4 = *(const float4*)&kv[128 + sl * 4];
        float4 v4 = *(const float4*)&kv[256 + sl * 4];
        float p = q4.x * k4.x + q4.y * k4.y + q4.z * k4.z + q4.w * k4.w;
        p += __shfl_xor(p, 1);
        p += __shfl_xor(p, 2);
        float s = valid ? p * 0.25f : -INFINITY;   // 1/sqrt(DH) = 0.25
        float mnew = fmaxf(m, s);
        if (mnew > -INFINITY) {
            float alpha = __expf(m - mnew);
            float w     = __expf(s - mnew);
            z = z * alpha + w;
            acc.x = acc.x * alpha + w * v4.x;
            acc.y = acc.y * alpha + w * v4.y;
            acc.z = acc.z * alpha + w * v4.z;
            acc.w = acc.w * alpha + w * v4.w;
            m = mnew;
        }
    }

    // merge the two 32-lane halves (lane pairs with lane^32, same sl)
    float m2 = __shfl_xor(m, 32);
    float z2 = __shfl_xor(z, 32);
    float ax = __shfl_xor(acc.x, 32);
    float ay = __shfl_xor(acc.y, 32);
    float az = __shfl_xor(acc.z, 32);
    float aw = __shfl_xor(acc.w, 32);
    float mm = fmaxf(m, m2);
    if (mm > -INFINITY) {
        float a1 = __expf(m - mm);
        float a2 = __expf(m2 - mm);
        z = z * a1 + z2 * a2;
        acc.x = acc.x * a1 + ax * a2;
        acc.y = acc.y * a1 + ay * a2;
        acc.z = acc.z * a1 + az * a2;
        acc.w = acc.w * a1 + aw * a2;
    }

    if (half == 0) {
        float inv = (z > 0.f) ? 1.0f / z : 0.f;
        float rr[4] = {acc.x * inv, acc.y * inv, acc.z * inv, acc.w * inv};
        #pragma unroll
        for (int jj = 0; jj < 4; ++jj) {
            int cp = sl * 4 + jj;          // head-major channel
            int d  = cp & 15;
            int hd = cp >> 4;
            out[(size_t)node * HID + d * 8 + hd] = rr[jj];   // reference layout
        }
    }
}

// ---------------------------------------------------------------------------
// Kernel 5: output projection via MFMA hi/lo split.  A = ob (reference
// layout), B = Wo (natural order).  4 waves x 32 cols = 128 cols.
// ---------------------------------------------------------------------------
__global__ __launch_bounds__(256)
void outproj_mfma_kernel(const float* __restrict__ A, int M,
                         const __bf16* __restrict__ Whi, const __bf16* __restrict__ Wlo,
                         const float* __restrict__ bo, float* __restrict__ C) {
    int tid  = threadIdx.x;
    int wv   = tid >> 6;
    int lane = tid & 63;
    int r    = lane & 15;
    int kg   = lane >> 4;
    int m0   = blockIdx.x * 64;
    int colbase = wv * 32;

    f32x4 acc[2][4];
    #pragma unroll
    for (int cf = 0; cf < 2; ++cf)
        #pragma unroll
        for (int rf = 0; rf < 4; ++rf)
            acc[cf][rf] = (f32x4){0.f, 0.f, 0.f, 0.f};

    #pragma unroll
    for (int t = 0; t < 4; ++t) {
        int k0 = t * 32 + kg * 8;
        bf16x8 Ahi[4], Alo[4];
        #pragma unroll
        for (int rf = 0; rf < 4; ++rf) {
            int mg = m0 + rf * 16 + r;
            if (mg > M - 1) mg = M - 1;
            const float* src = &A[(size_t)mg * HID + k0];
            float4 x0 = *(const float4*)src;
            float4 x1 = *(const float4*)(src + 4);
            float xs[8] = {x0.x, x0.y, x0.z, x0.w, x1.x, x1.y, x1.z, x1.w};
            #pragma unroll
            for (int e = 0; e < 8; ++e) {
                __bf16 hv = (__bf16)xs[e];
                Ahi[rf][e] = hv;
                Alo[rf][e] = (__bf16)(xs[e] - (float)hv);
            }
        }
        #pragma unroll
        for (int cf = 0; cf < 2; ++cf) {
            int wrow = (colbase + cf * 16 + r) * 128;     // Wo row = output col
            bf16x8 bh = *(const bf16x8*)&Whi[wrow + k0];
            bf16x8 bl = *(const bf16x8*)&Wlo[wrow + k0];
            #pragma unroll
            for (int rf = 0; rf < 4; ++rf) {
                acc[cf][rf] = __builtin_amdgcn_mfma_f32_16x16x32_bf16(Ahi[rf], bh, acc[cf][rf], 0, 0, 0);
                acc[cf][rf] = __builtin_amdgcn_mfma_f32_16x16x32_bf16(Alo[rf], bh, acc[cf][rf], 0, 0, 0);
                acc[cf][rf] = __builtin_amdgcn_mfma_f32_16x16x32_bf16(Ahi[rf], bl, acc[cf][rf], 0, 0, 0);
            }
        }
    }

    int orow = (lane >> 4) * 4;
    #pragma unroll
    for (int cf = 0; cf < 2; ++cf) {
        int col = colbase + cf * 16 + r;
        float b = bo[col];
        #pragma unroll
        for (int rf = 0; rf < 4; ++rf) {
            #pragma unroll
            for (int e = 0; e < 4; ++e) {
                int mg = m0 + rf * 16 + orow + e;
                if (mg < M) C[(size_t)mg * HID + col] = acc[cf][rf][e] + b;
            }
        }
    }
}

// ---------------------------------------------------------------------------
extern "C" void kernel_launch(void* const* d_in, const int* in_sizes, int n_in,
                              void* d_out, int out_size, void* d_ws, size_t ws_size,
                              hipStream_t stream) {
    const float* h  = (const float*)d_in[0];
    const int* row  = (const int*)d_in[1];
    const int* col  = (const int*)d_in[2];
    const float* Wq = (const float*)d_in[3];
    const float* bq = (const float*)d_in[4];
    const float* Wk = (const float*)d_in[5];
    const float* bk = (const float*)d_in[6];
    const float* Wv = (const float*)d_in[7];
    const float* bv = (const float*)d_in[8];
    const float* Wo = (const float*)d_in[9];
    const float* bo = (const float*)d_in[10];
    float* out = (float*)d_out;

    int N_ = in_sizes[0] / HID;   // 50000
    int E_ = in_sizes[1];         // 800000

    char* ws = (char*)d_ws;
    size_t off = 0;
    auto alloc = [&](size_t bytes) {
        void* p = (void*)(ws + off);
        off = (off + bytes + 255) & ~(size_t)255;
        return p;
    };
    int*    row_ptr = (int*)   alloc((size_t)(N_ + 1) * sizeof(int));
    float*  qkv     = (float*) alloc((size_t)N_ * 384 * sizeof(float));
    float*  ob      = (float*) alloc((size_t)N_ * HID * sizeof(float));
    __bf16* Whi     = (__bf16*)alloc((size_t)4 * 16384 * sizeof(__bf16));
    __bf16* Wlo     = (__bf16*)alloc((size_t)4 * 16384 * sizeof(__bf16));
    float*  bias384 = (float*) alloc(384 * sizeof(float));
    (void)ws_size;

    wsplit_kernel<<<256, 256, 0, stream>>>(Wq, Wk, Wv, Wo, bq, bk, bv, Whi, Wlo, bias384);
    rowptr_kernel<<<(N_ + 256) / 256, 256, 0, stream>>>(row, row_ptr, N_, E_);
    qkv_mfma_kernel<<<(N_ + 63) / 64, 256, 0, stream>>>(h, N_, Whi, Wlo, bias384, qkv);
    edge_attn_kernel<<<(N_ + 3) / 4, 256, 0, stream>>>(row_ptr, col, qkv, ob, N_);
    outproj_mfma_kernel<<<(N_ + 63) / 64, 256, 0, stream>>>(
        ob, N_, Whi + 3 * 16384, Wlo + 3 * 16384, bo, out);
}

// Round 3
// 248.305 us; speedup vs baseline: 1.5829x; 1.2282x over previous
//
#include <hip/hip_runtime.h>
#include <hip/hip_bf16.h>
#include <math.h>

#define HID 128
#define NH 8
#define DH 16

typedef __bf16 bf16x8 __attribute__((ext_vector_type(8)));
typedef float  f32x4  __attribute__((ext_vector_type(4)));

// ---------------------------------------------------------------------------
// Kernel 1 (prep): fused rowptr binary-search + W hi/lo split + bias384.
// ---------------------------------------------------------------------------
__global__ void prep_kernel(const int* __restrict__ row, int* __restrict__ row_ptr,
                            int N_, int E_,
                            const float* __restrict__ Wq, const float* __restrict__ Wk,
                            const float* __restrict__ Wv, const float* __restrict__ Wo,
                            const float* __restrict__ bq, const float* __restrict__ bk,
                            const float* __restrict__ bv,
                            __bf16* __restrict__ Whi, __bf16* __restrict__ Wlo,
                            float* __restrict__ bias384) {
    int idx = blockIdx.x * blockDim.x + threadIdx.x;
    if (idx < 4 * 16384) {
        int j = idx >> 14;
        int rem = idx & 16383;
        const float* W = (j == 0) ? Wq : (j == 1) ? Wk : (j == 2) ? Wv : Wo;
        float x = W[rem];
        __bf16 hv = (__bf16)x;
        Whi[idx] = hv;
        Wlo[idx] = (__bf16)(x - (float)hv);
    }
    if (idx <= N_) {
        int lo = 0, hi = E_;
        while (lo < hi) {
            int mid = (lo + hi) >> 1;
            if (row[mid] < idx) lo = mid + 1; else hi = mid;
        }
        row_ptr[idx] = lo;
    }
    if (idx < 384) {
        int j = idx >> 7;
        int pcol = idx & 127;                       // head-major col within proj
        int o = ((pcol & 15) << 3) | (pcol >> 4);   // original W row
        const float* b = (j == 0) ? bq : (j == 1) ? bk : bv;
        bias384[idx] = b[o];
    }
}

// ---------------------------------------------------------------------------
// Kernel 2: fused QKV projection via MFMA (bf16 hi/lo split = fp32 accuracy).
// 4 waves x 96 fused cols (q128|k128|v128, head-major). q stored fp32
// [N][128]; k,v stored bf16 interleaved kv[N][256]: group g holds
// {k[4g..4g+3], v[4g..4g+3]} so an edge lane reads one dwordx4.
// ---------------------------------------------------------------------------
__global__ __launch_bounds__(256)
void qkv_mfma_kernel(const float* __restrict__ h, int M,
                     const __bf16* __restrict__ Whi, const __bf16* __restrict__ Wlo,
                     const float* __restrict__ bias384,
                     float* __restrict__ q, __bf16* __restrict__ kv) {
    int tid  = threadIdx.x;
    int wv   = tid >> 6;
    int lane = tid & 63;
    int r    = lane & 15;
    int kg   = lane >> 4;
    int m0   = blockIdx.x * 64;
    int colbase = wv * 96;

    f32x4 acc[6][4];
    #pragma unroll
    for (int cf = 0; cf < 6; ++cf)
        #pragma unroll
        for (int rf = 0; rf < 4; ++rf)
            acc[cf][rf] = (f32x4){0.f, 0.f, 0.f, 0.f};

    int wrow[6];
    #pragma unroll
    for (int cf = 0; cf < 6; ++cf) {
        int col  = colbase + cf * 16 + r;
        int j    = col >> 7;
        int pcol = col & 127;
        int o    = ((pcol & 15) << 3) | (pcol >> 4);
        wrow[cf] = (j * 128 + o) * 128;
    }

    #pragma unroll
    for (int t = 0; t < 4; ++t) {
        int k0 = t * 32 + kg * 8;
        bf16x8 Ahi[4], Alo[4];
        #pragma unroll
        for (int rf = 0; rf < 4; ++rf) {
            int mg = m0 + rf * 16 + r;
            if (mg > M - 1) mg = M - 1;
            const float* src = &h[(size_t)mg * HID + k0];
            float4 x0 = *(const float4*)src;
            float4 x1 = *(const float4*)(src + 4);
            float xs[8] = {x0.x, x0.y, x0.z, x0.w, x1.x, x1.y, x1.z, x1.w};
            #pragma unroll
            for (int e = 0; e < 8; ++e) {
                __bf16 hv = (__bf16)xs[e];
                Ahi[rf][e] = hv;
                Alo[rf][e] = (__bf16)(xs[e] - (float)hv);
            }
        }
        #pragma unroll
        for (int cf = 0; cf < 6; ++cf) {
            bf16x8 bh = *(const bf16x8*)&Whi[wrow[cf] + k0];
            bf16x8 bl = *(const bf16x8*)&Wlo[wrow[cf] + k0];
            #pragma unroll
            for (int rf = 0; rf < 4; ++rf) {
                acc[cf][rf] = __builtin_amdgcn_mfma_f32_16x16x32_bf16(Ahi[rf], bh, acc[cf][rf], 0, 0, 0);
                acc[cf][rf] = __builtin_amdgcn_mfma_f32_16x16x32_bf16(Alo[rf], bh, acc[cf][rf], 0, 0, 0);
                acc[cf][rf] = __builtin_amdgcn_mfma_f32_16x16x32_bf16(Ahi[rf], bl, acc[cf][rf], 0, 0, 0);
            }
        }
    }

    // epilogue: C layout col = lane&15, row = (lane>>4)*4 + e
    int orow = (lane >> 4) * 4;
    #pragma unroll
    for (int cf = 0; cf < 6; ++cf) {
        int col  = colbase + cf * 16 + r;
        int j    = col >> 7;          // uniform per fragment
        int pcol = col & 127;
        float b  = bias384[col];
        #pragma unroll
        for (int rf = 0; rf < 4; ++rf) {
            #pragma unroll
            for (int e = 0; e < 4; ++e) {
                int mg = m0 + rf * 16 + orow + e;
                if (mg >= M) continue;
                float val = acc[cf][rf][e] + b;
                if (j == 0) {
                    q[(size_t)mg * 128 + pcol] = val;
                } else {
                    int g   = pcol >> 2;
                    int idx = g * 8 + ((j == 1) ? 0 : 4) + (pcol & 3);
                    kv[(size_t)mg * 256 + idx] = (__bf16)val;
                }
            }
        }
    }
}

// ---------------------------------------------------------------------------
// Kernel 3: fused SDDMM + online segment-softmax + SPMM.
// One wave per node; halves (32+32) each process 2 edges per main-loop iter
// (4 edges in flight).  Lane sl owns head-major channels 4sl..4sl+3; one
// dwordx4 per edge delivers k4|v4 (bf16).  Output in reference layout.
// ---------------------------------------------------------------------------
__device__ __forceinline__ float blo(unsigned u) { return __uint_as_float(u << 16); }
__device__ __forceinline__ float bhi(unsigned u) { return __uint_as_float(u & 0xffff0000u); }

__global__ __launch_bounds__(256)
void edge_attn_kernel(const int* __restrict__ row_ptr, const int* __restrict__ col,
                      const float* __restrict__ q, const __bf16* __restrict__ kv,
                      float* __restrict__ out, int N_) {
    int wave = threadIdx.x >> 6;
    int lane = threadIdx.x & 63;
    int node = blockIdx.x * 4 + wave;
    if (node >= N_) return;
    int sl   = lane & 31;
    int half = lane >> 5;

    float4 q4 = *(const float4*)&q[(size_t)node * 128 + sl * 4];
    int e0 = row_ptr[node];
    int e1 = row_ptr[node + 1];

    float m = -INFINITY, z = 0.f;
    float4 acc = make_float4(0.f, 0.f, 0.f, 0.f);

    auto score = [&](uint4 u) {
        float p = q4.x * blo(u.x) + q4.y * bhi(u.x) +
                  q4.z * blo(u.y) + q4.w * bhi(u.y);
        p += __shfl_xor(p, 1);
        p += __shfl_xor(p, 2);
        return p * 0.25f;                       // 1/sqrt(DH)
    };
    auto update = [&](float s, uint4 u) {
        float mnew  = fmaxf(m, s);
        float alpha = __expf(m - mnew);         // m=-inf,s finite -> 0, ok
        float w     = __expf(s - mnew);
        z = z * alpha + w;
        acc.x = acc.x * alpha + w * blo(u.z);
        acc.y = acc.y * alpha + w * bhi(u.z);
        acc.z = acc.z * alpha + w * blo(u.w);
        acc.w = acc.w * alpha + w * bhi(u.w);
        m = mnew;
    };

    int eb = e0;
    // main loop: 4 valid edges per iter (2 per half), no masking
    for (; eb + 4 <= e1; eb += 4) {
        int ea = eb + half * 2;
        int c0 = col[ea];
        int c1 = col[ea + 1];
        uint4 u0 = *(const uint4*)(kv + (size_t)c0 * 256 + sl * 8);
        uint4 u1 = *(const uint4*)(kv + (size_t)c1 * 256 + sl * 8);
        float s0 = score(u0);
        float s1 = score(u1);
        update(s0, u0);
        update(s1, u1);
    }
    // tail: up to 3 edges, masked (2 per iter across halves)
    for (; eb < e1; eb += 2) {
        int my_e   = eb + half;
        bool valid = (my_e < e1);
        int cnode  = valid ? col[my_e] : col[eb];
        uint4 u = *(const uint4*)(kv + (size_t)cnode * 256 + sl * 8);
        float s = valid ? score(u) : -INFINITY;
        float mnew = fmaxf(m, s);
        if (mnew > -INFINITY) {
            float alpha = __expf(m - mnew);
            float w     = __expf(s - mnew);
            z = z * alpha + w;
            acc.x = acc.x * alpha + w * blo(u.z);
            acc.y = acc.y * alpha + w * bhi(u.z);
            acc.z = acc.z * alpha + w * blo(u.w);
            acc.w = acc.w * alpha + w * bhi(u.w);
            m = mnew;
        }
    }

    // merge the two halves (lane pairs with lane^32, same sl)
    float m2 = __shfl_xor(m, 32);
    float z2 = __shfl_xor(z, 32);
    float ax = __shfl_xor(acc.x, 32);
    float ay = __shfl_xor(acc.y, 32);
    float az = __shfl_xor(acc.z, 32);
    float aw = __shfl_xor(acc.w, 32);
    float mm = fmaxf(m, m2);
    if (mm > -INFINITY) {
        float a1 = __expf(m - mm);
        float a2 = __expf(m2 - mm);
        z = z * a1 + z2 * a2;
        acc.x = acc.x * a1 + ax * a2;
        acc.y = acc.y * a1 + ay * a2;
        acc.z = acc.z * a1 + az * a2;
        acc.w = acc.w * a1 + aw * a2;
    }

    if (half == 0) {
        float inv = (z > 0.f) ? 1.0f / z : 0.f;
        float rr[4] = {acc.x * inv, acc.y * inv, acc.z * inv, acc.w * inv};
        #pragma unroll
        for (int jj = 0; jj < 4; ++jj) {
            int cp = sl * 4 + jj;          // head-major channel
            int d  = cp & 15;
            int hd = cp >> 4;
            out[(size_t)node * HID + d * 8 + hd] = rr[jj];   // reference layout
        }
    }
}

// ---------------------------------------------------------------------------
// Kernel 4: output projection via MFMA hi/lo split (natural layouts).
// ---------------------------------------------------------------------------
__global__ __launch_bounds__(256)
void outproj_mfma_kernel(const float* __restrict__ A, int M,
                         const __bf16* __restrict__ Whi, const __bf16* __restrict__ Wlo,
                         const float* __restrict__ bo, float* __restrict__ C) {
    int tid  = threadIdx.x;
    int wv   = tid >> 6;
    int lane = tid & 63;
    int r    = lane & 15;
    int kg   = lane >> 4;
    int m0   = blockIdx.x * 64;
    int colbase = wv * 32;

    f32x4 acc[2][4];
    #pragma unroll
    for (int cf = 0; cf < 2; ++cf)
        #pragma unroll
        for (int rf = 0; rf < 4; ++rf)
            acc[cf][rf] = (f32x4){0.f, 0.f, 0.f, 0.f};

    #pragma unroll
    for (int t = 0; t < 4; ++t) {
        int k0 = t * 32 + kg * 8;
        bf16x8 Ahi[4], Alo[4];
        #pragma unroll
        for (int rf = 0; rf < 4; ++rf) {
            int mg = m0 + rf * 16 + r;
            if (mg > M - 1) mg = M - 1;
            const float* src = &A[(size_t)mg * HID + k0];
            float4 x0 = *(const float4*)src;
            float4 x1 = *(const float4*)(src + 4);
            float xs[8] = {x0.x, x0.y, x0.z, x0.w, x1.x, x1.y, x1.z, x1.w};
            #pragma unroll
            for (int e = 0; e < 8; ++e) {
                __bf16 hv = (__bf16)xs[e];
                Ahi[rf][e] = hv;
                Alo[rf][e] = (__bf16)(xs[e] - (float)hv);
            }
        }
        #pragma unroll
        for (int cf = 0; cf < 2; ++cf) {
            int wrow = (colbase + cf * 16 + r) * 128;
            bf16x8 bh = *(const bf16x8*)&Whi[wrow + k0];
            bf16x8 bl = *(const bf16x8*)&Wlo[wrow + k0];
            #pragma unroll
            for (int rf = 0; rf < 4; ++rf) {
                acc[cf][rf] = __builtin_amdgcn_mfma_f32_16x16x32_bf16(Ahi[rf], bh, acc[cf][rf], 0, 0, 0);
                acc[cf][rf] = __builtin_amdgcn_mfma_f32_16x16x32_bf16(Alo[rf], bh, acc[cf][rf], 0, 0, 0);
                acc[cf][rf] = __builtin_amdgcn_mfma_f32_16x16x32_bf16(Ahi[rf], bl, acc[cf][rf], 0, 0, 0);
            }
        }
    }

    int orow = (lane >> 4) * 4;
    #pragma unroll
    for (int cf = 0; cf < 2; ++cf) {
        int col = colbase + cf * 16 + r;
        float b = bo[col];
        #pragma unroll
        for (int rf = 0; rf < 4; ++rf) {
            #pragma unroll
            for (int e = 0; e < 4; ++e) {
                int mg = m0 + rf * 16 + orow + e;
                if (mg < M) C[(size_t)mg * HID + col] = acc[cf][rf][e] + b;
            }
        }
    }
}

// ---------------------------------------------------------------------------
extern "C" void kernel_launch(void* const* d_in, const int* in_sizes, int n_in,
                              void* d_out, int out_size, void* d_ws, size_t ws_size,
                              hipStream_t stream) {
    const float* h  = (const float*)d_in[0];
    const int* row  = (const int*)d_in[1];
    const int* col  = (const int*)d_in[2];
    const float* Wq = (const float*)d_in[3];
    const float* bq = (const float*)d_in[4];
    const float* Wk = (const float*)d_in[5];
    const float* bk = (const float*)d_in[6];
    const float* Wv = (const float*)d_in[7];
    const float* bv = (const float*)d_in[8];
    const float* Wo = (const float*)d_in[9];
    const float* bo = (const float*)d_in[10];
    float* out = (float*)d_out;

    int N_ = in_sizes[0] / HID;   // 50000
    int E_ = in_sizes[1];         // 800000

    char* ws = (char*)d_ws;
    size_t off = 0;
    auto alloc = [&](size_t bytes) {
        void* p = (void*)(ws + off);
        off = (off + bytes + 255) & ~(size_t)255;
        return p;
    };
    int*    row_ptr = (int*)   alloc((size_t)(N_ + 1) * sizeof(int));
    float*  qb      = (float*) alloc((size_t)N_ * 128 * sizeof(float));
    __bf16* kvb     = (__bf16*)alloc((size_t)N_ * 256 * sizeof(__bf16));
    float*  ob      = (float*) alloc((size_t)N_ * HID * sizeof(float));
    __bf16* Whi     = (__bf16*)alloc((size_t)4 * 16384 * sizeof(__bf16));
    __bf16* Wlo     = (__bf16*)alloc((size_t)4 * 16384 * sizeof(__bf16));
    float*  bias384 = (float*) alloc(384 * sizeof(float));
    (void)ws_size;

    prep_kernel<<<256, 256, 0, stream>>>(row, row_ptr, N_, E_,
                                         Wq, Wk, Wv, Wo, bq, bk, bv,
                                         Whi, Wlo, bias384);
    qkv_mfma_kernel<<<(N_ + 63) / 64, 256, 0, stream>>>(h, N_, Whi, Wlo, bias384, qb, kvb);
    edge_attn_kernel<<<(N_ + 3) / 4, 256, 0, stream>>>(row_ptr, col, qb, kvb, ob, N_);
    outproj_mfma_kernel<<<(N_ + 63) / 64, 256, 0, stream>>>(
        ob, N_, Whi + 3 * 16384, Wlo + 3 * 16384, bo, out);
}

// Round 4
// 216.914 us; speedup vs baseline: 1.8120x; 1.1447x over previous
//
#include <hip/hip_runtime.h>
#include <hip/hip_bf16.h>
#include <math.h>

#define HID 128
#define NH 8
#define DH 16

typedef __bf16 bf16x8 __attribute__((ext_vector_type(8)));
typedef float  f32x4  __attribute__((ext_vector_type(4)));

// ---------------------------------------------------------------------------
// Kernel 1 (prep): fused rowptr binary-search + W hi/lo split + bias384.
// ---------------------------------------------------------------------------
__global__ void prep_kernel(const int* __restrict__ row, int* __restrict__ row_ptr,
                            int N_, int E_,
                            const float* __restrict__ Wq, const float* __restrict__ Wk,
                            const float* __restrict__ Wv, const float* __restrict__ Wo,
                            const float* __restrict__ bq, const float* __restrict__ bk,
                            const float* __restrict__ bv,
                            __bf16* __restrict__ Whi, __bf16* __restrict__ Wlo,
                            float* __restrict__ bias384) {
    int idx = blockIdx.x * blockDim.x + threadIdx.x;
    if (idx < 4 * 16384) {
        int j = idx >> 14;
        int rem = idx & 16383;
        const float* W = (j == 0) ? Wq : (j == 1) ? Wk : (j == 2) ? Wv : Wo;
        float x = W[rem];
        __bf16 hv = (__bf16)x;
        Whi[idx] = hv;
        Wlo[idx] = (__bf16)(x - (float)hv);
    }
    if (idx <= N_) {
        int lo = 0, hi = E_;
        while (lo < hi) {
            int mid = (lo + hi) >> 1;
            if (row[mid] < idx) lo = mid + 1; else hi = mid;
        }
        row_ptr[idx] = lo;
    }
    if (idx < 384) {
        int j = idx >> 7;
        int pcol = idx & 127;                       // head-major col within proj
        int o = ((pcol & 15) << 3) | (pcol >> 4);   // original W row
        const float* b = (j == 0) ? bq : (j == 1) ? bk : bv;
        bias384[idx] = b[o];
    }
}

// ---------------------------------------------------------------------------
// Kernel 2: fused QKV projection via MFMA (bf16 hi/lo split = fp32 accuracy).
// A-tile (64 rows x 128 f32) staged in LDS with coalesced loads and XOR
// bank-swizzle (col4' = col4 ^ (row&7)); fragments read via ds_read_b128
// (2-way bank alias = free).  q stored fp32 [N][128] head-major (direct
// 64B-segment stores); k,v stored bf16 interleaved kv[N][256] via an LDS
// transpose so the global store is fully coalesced uint4.
// ---------------------------------------------------------------------------
__global__ __launch_bounds__(256)
void qkv_mfma_kernel(const float* __restrict__ h, int M,
                     const __bf16* __restrict__ Whi, const __bf16* __restrict__ Wlo,
                     const float* __restrict__ bias384,
                     float* __restrict__ q, __bf16* __restrict__ kv) {
    __shared__ float As[64 * 128];          // 32 KB; reused as bf16 kv buffer
    int tid  = threadIdx.x;
    int wv   = tid >> 6;
    int lane = tid & 63;
    int r    = lane & 15;
    int kg   = lane >> 4;
    int m0   = blockIdx.x * 64;
    int colbase = wv * 96;

    // ---- stage A tile, coalesced global reads, swizzled LDS layout ----
    #pragma unroll
    for (int it = 0; it < 8; ++it) {
        int flat = it * 256 + tid;          // float4 slot 0..2047
        int row  = flat >> 5;               // 0..63
        int s    = flat & 31;               // LDS col4 slot
        int g    = s ^ (row & 7);           // global col4 (involution)
        int grow = m0 + row; if (grow > M - 1) grow = M - 1;
        *(float4*)&As[row * 128 + s * 4] =
            *(const float4*)&h[(size_t)grow * 128 + g * 4];
    }
    __syncthreads();

    f32x4 acc[6][4];
    #pragma unroll
    for (int cf = 0; cf < 6; ++cf)
        #pragma unroll
        for (int rf = 0; rf < 4; ++rf)
            acc[cf][rf] = (f32x4){0.f, 0.f, 0.f, 0.f};

    int wrow[6];
    #pragma unroll
    for (int cf = 0; cf < 6; ++cf) {
        int col  = colbase + cf * 16 + r;
        int j    = col >> 7;
        int pcol = col & 127;
        int o    = ((pcol & 15) << 3) | (pcol >> 4);
        wrow[cf] = (j * 128 + o) * 128;
    }

    #pragma unroll
    for (int t = 0; t < 4; ++t) {
        int k0 = t * 32 + kg * 8;
        int c0 = k0 >> 2;                   // even col4 index
        bf16x8 Ahi[4], Alo[4];
        #pragma unroll
        for (int rf = 0; rf < 4; ++rf) {
            int row = rf * 16 + r;
            int sw  = row & 7;
            float4 xa = *(float4*)&As[row * 128 + ((c0    ) ^ sw) * 4];
            float4 xb = *(float4*)&As[row * 128 + ((c0 + 1) ^ sw) * 4];
            float xs[8] = {xa.x, xa.y, xa.z, xa.w, xb.x, xb.y, xb.z, xb.w};
            #pragma unroll
            for (int e = 0; e < 8; ++e) {
                __bf16 hv = (__bf16)xs[e];
                Ahi[rf][e] = hv;
                Alo[rf][e] = (__bf16)(xs[e] - (float)hv);
            }
        }
        #pragma unroll
        for (int cf = 0; cf < 6; ++cf) {
            bf16x8 bh = *(const bf16x8*)&Whi[wrow[cf] + k0];
            bf16x8 bl = *(const bf16x8*)&Wlo[wrow[cf] + k0];
            #pragma unroll
            for (int rf = 0; rf < 4; ++rf) {
                acc[cf][rf] = __builtin_amdgcn_mfma_f32_16x16x32_bf16(Ahi[rf], bh, acc[cf][rf], 0, 0, 0);
                acc[cf][rf] = __builtin_amdgcn_mfma_f32_16x16x32_bf16(Alo[rf], bh, acc[cf][rf], 0, 0, 0);
                acc[cf][rf] = __builtin_amdgcn_mfma_f32_16x16x32_bf16(Ahi[rf], bl, acc[cf][rf], 0, 0, 0);
            }
        }
    }

    // ---- epilogue: q direct; kv through LDS for coalesced stores ----
    __syncthreads();                        // all As reads done; reuse buffer
    __bf16* kvs = (__bf16*)As;              // 64 x 256 bf16 = 32 KB
    int orow = kg * 4;
    #pragma unroll
    for (int cf = 0; cf < 6; ++cf) {
        int col  = colbase + cf * 16 + r;
        int j    = col >> 7;                // 0=q 1=k 2=v (uniform per cf)
        int pcol = col & 127;
        float b  = bias384[col];
        #pragma unroll
        for (int rf = 0; rf < 4; ++rf) {
            #pragma unroll
            for (int e = 0; e < 4; ++e) {
                int mrow = rf * 16 + orow + e;      // 0..63
                float val = acc[cf][rf][e] + b;
                if (j == 0) {
                    int mg = m0 + mrow;
                    if (mg < M) q[(size_t)mg * 128 + pcol] = val;
                } else {
                    int gi  = pcol >> 2;
                    int idx = gi * 8 + ((j == 1) ? 0 : 4) + (pcol & 3);
                    kvs[mrow * 256 + idx] = (__bf16)val;
                }
            }
        }
    }
    __syncthreads();
    #pragma unroll
    for (int it = 0; it < 8; ++it) {
        int flat = it * 256 + tid;          // 16B chunk 0..2047
        int row  = flat >> 5;
        int c    = flat & 31;
        int mg   = m0 + row;
        if (mg < M)
            *(uint4*)&kv[(size_t)mg * 256 + c * 8] = *(uint4*)&kvs[row * 256 + c * 8];
    }
}

// ---------------------------------------------------------------------------
// Kernel 3: fused SDDMM + online segment-softmax + SPMM.
// One wave per node; halves (32+32) each process 2 edges per main-loop iter.
// Lane sl owns head-major channels 4sl..4sl+3; one dwordx4 per edge delivers
// k4|v4 (bf16).  Output in reference layout.
// ---------------------------------------------------------------------------
__device__ __forceinline__ float blo(unsigned u) { return __uint_as_float(u << 16); }
__device__ __forceinline__ float bhi(unsigned u) { return __uint_as_float(u & 0xffff0000u); }

__global__ __launch_bounds__(256)
void edge_attn_kernel(const int* __restrict__ row_ptr, const int* __restrict__ col,
                      const float* __restrict__ q, const __bf16* __restrict__ kv,
                      float* __restrict__ out, int N_) {
    int wave = threadIdx.x >> 6;
    int lane = threadIdx.x & 63;
    int node = blockIdx.x * 4 + wave;
    if (node >= N_) return;
    int sl   = lane & 31;
    int half = lane >> 5;

    float4 q4 = *(const float4*)&q[(size_t)node * 128 + sl * 4];
    int e0 = row_ptr[node];
    int e1 = row_ptr[node + 1];

    float m = -INFINITY, z = 0.f;
    float4 acc = make_float4(0.f, 0.f, 0.f, 0.f);

    auto score = [&](uint4 u) {
        float p = q4.x * blo(u.x) + q4.y * bhi(u.x) +
                  q4.z * blo(u.y) + q4.w * bhi(u.y);
        p += __shfl_xor(p, 1);
        p += __shfl_xor(p, 2);
        return p * 0.25f;                       // 1/sqrt(DH)
    };
    auto update = [&](float s, uint4 u) {
        float mnew  = fmaxf(m, s);
        float alpha = __expf(m - mnew);
        float w     = __expf(s - mnew);
        z = z * alpha + w;
        acc.x = acc.x * alpha + w * blo(u.z);
        acc.y = acc.y * alpha + w * bhi(u.z);
        acc.z = acc.z * alpha + w * blo(u.w);
        acc.w = acc.w * alpha + w * bhi(u.w);
        m = mnew;
    };

    int eb = e0;
    for (; eb + 4 <= e1; eb += 4) {
        int ea = eb + half * 2;
        int c0 = col[ea];
        int c1 = col[ea + 1];
        uint4 u0 = *(const uint4*)(kv + (size_t)c0 * 256 + sl * 8);
        uint4 u1 = *(const uint4*)(kv + (size_t)c1 * 256 + sl * 8);
        float s0 = score(u0);
        float s1 = score(u1);
        update(s0, u0);
        update(s1, u1);
    }
    for (; eb < e1; eb += 2) {
        int my_e   = eb + half;
        bool valid = (my_e < e1);
        int cnode  = valid ? col[my_e] : col[eb];
        uint4 u = *(const uint4*)(kv + (size_t)cnode * 256 + sl * 8);
        float s = valid ? score(u) : -INFINITY;
        float mnew = fmaxf(m, s);
        if (mnew > -INFINITY) {
            float alpha = __expf(m - mnew);
            float w     = __expf(s - mnew);
            z = z * alpha + w;
            acc.x = acc.x * alpha + w * blo(u.z);
            acc.y = acc.y * alpha + w * bhi(u.z);
            acc.z = acc.z * alpha + w * blo(u.w);
            acc.w = acc.w * alpha + w * bhi(u.w);
            m = mnew;
        }
    }

    float m2 = __shfl_xor(m, 32);
    float z2 = __shfl_xor(z, 32);
    float ax = __shfl_xor(acc.x, 32);
    float ay = __shfl_xor(acc.y, 32);
    float az = __shfl_xor(acc.z, 32);
    float aw = __shfl_xor(acc.w, 32);
    float mm = fmaxf(m, m2);
    if (mm > -INFINITY) {
        float a1 = __expf(m - mm);
        float a2 = __expf(m2 - mm);
        z = z * a1 + z2 * a2;
        acc.x = acc.x * a1 + ax * a2;
        acc.y = acc.y * a1 + ay * a2;
        acc.z = acc.z * a1 + az * a2;
        acc.w = acc.w * a1 + aw * a2;
    }

    if (half == 0) {
        float inv = (z > 0.f) ? 1.0f / z : 0.f;
        float rr[4] = {acc.x * inv, acc.y * inv, acc.z * inv, acc.w * inv};
        #pragma unroll
        for (int jj = 0; jj < 4; ++jj) {
            int cp = sl * 4 + jj;
            int d  = cp & 15;
            int hd = cp >> 4;
            out[(size_t)node * HID + d * 8 + hd] = rr[jj];
        }
    }
}

// ---------------------------------------------------------------------------
// Kernel 4: output projection via MFMA hi/lo split, LDS-staged A tile
// (same swizzled staging as kernel 2).
// ---------------------------------------------------------------------------
__global__ __launch_bounds__(256)
void outproj_mfma_kernel(const float* __restrict__ A, int M,
                         const __bf16* __restrict__ Whi, const __bf16* __restrict__ Wlo,
                         const float* __restrict__ bo, float* __restrict__ C) {
    __shared__ float As[64 * 128];
    int tid  = threadIdx.x;
    int wv   = tid >> 6;
    int lane = tid & 63;
    int r    = lane & 15;
    int kg   = lane >> 4;
    int m0   = blockIdx.x * 64;
    int colbase = wv * 32;

    #pragma unroll
    for (int it = 0; it < 8; ++it) {
        int flat = it * 256 + tid;
        int row  = flat >> 5;
        int s    = flat & 31;
        int g    = s ^ (row & 7);
        int grow = m0 + row; if (grow > M - 1) grow = M - 1;
        *(float4*)&As[row * 128 + s * 4] =
            *(const float4*)&A[(size_t)grow * 128 + g * 4];
    }
    __syncthreads();

    f32x4 acc[2][4];
    #pragma unroll
    for (int cf = 0; cf < 2; ++cf)
        #pragma unroll
        for (int rf = 0; rf < 4; ++rf)
            acc[cf][rf] = (f32x4){0.f, 0.f, 0.f, 0.f};

    #pragma unroll
    for (int t = 0; t < 4; ++t) {
        int k0 = t * 32 + kg * 8;
        int c0 = k0 >> 2;
        bf16x8 Ahi[4], Alo[4];
        #pragma unroll
        for (int rf = 0; rf < 4; ++rf) {
            int row = rf * 16 + r;
            int sw  = row & 7;
            float4 xa = *(float4*)&As[row * 128 + ((c0    ) ^ sw) * 4];
            float4 xb = *(float4*)&As[row * 128 + ((c0 + 1) ^ sw) * 4];
            float xs[8] = {xa.x, xa.y, xa.z, xa.w, xb.x, xb.y, xb.z, xb.w};
            #pragma unroll
            for (int e = 0; e < 8; ++e) {
                __bf16 hv = (__bf16)xs[e];
                Ahi[rf][e] = hv;
                Alo[rf][e] = (__bf16)(xs[e] - (float)hv);
            }
        }
        #pragma unroll
        for (int cf = 0; cf < 2; ++cf) {
            int wrow = (colbase + cf * 16 + r) * 128;
            bf16x8 bh = *(const bf16x8*)&Whi[wrow + k0];
            bf16x8 bl = *(const bf16x8*)&Wlo[wrow + k0];
            #pragma unroll
            for (int rf = 0; rf < 4; ++rf) {
                acc[cf][rf] = __builtin_amdgcn_mfma_f32_16x16x32_bf16(Ahi[rf], bh, acc[cf][rf], 0, 0, 0);
                acc[cf][rf] = __builtin_amdgcn_mfma_f32_16x16x32_bf16(Alo[rf], bh, acc[cf][rf], 0, 0, 0);
                acc[cf][rf] = __builtin_amdgcn_mfma_f32_16x16x32_bf16(Ahi[rf], bl, acc[cf][rf], 0, 0, 0);
            }
        }
    }

    int orow = kg * 4;
    #pragma unroll
    for (int cf = 0; cf < 2; ++cf) {
        int col = colbase + cf * 16 + r;
        float b = bo[col];
        #pragma unroll
        for (int rf = 0; rf < 4; ++rf) {
            #pragma unroll
            for (int e = 0; e < 4; ++e) {
                int mg = m0 + rf * 16 + orow + e;
                if (mg < M) C[(size_t)mg * HID + col] = acc[cf][rf][e] + b;
            }
        }
    }
}

// ---------------------------------------------------------------------------
extern "C" void kernel_launch(void* const* d_in, const int* in_sizes, int n_in,
                              void* d_out, int out_size, void* d_ws, size_t ws_size,
                              hipStream_t stream) {
    const float* h  = (const float*)d_in[0];
    const int* row  = (const int*)d_in[1];
    const int* col  = (const int*)d_in[2];
    const float* Wq = (const float*)d_in[3];
    const float* bq = (const float*)d_in[4];
    const float* Wk = (const float*)d_in[5];
    const float* bk = (const float*)d_in[6];
    const float* Wv = (const float*)d_in[7];
    const float* bv = (const float*)d_in[8];
    const float* Wo = (const float*)d_in[9];
    const float* bo = (const float*)d_in[10];
    float* out = (float*)d_out;

    int N_ = in_sizes[0] / HID;   // 50000
    int E_ = in_sizes[1];         // 800000

    char* ws = (char*)d_ws;
    size_t off = 0;
    auto alloc = [&](size_t bytes) {
        void* p = (void*)(ws + off);
        off = (off + bytes + 255) & ~(size_t)255;
        return p;
    };
    int*    row_ptr = (int*)   alloc((size_t)(N_ + 1) * sizeof(int));
    float*  qb      = (float*) alloc((size_t)N_ * 128 * sizeof(float));
    __bf16* kvb     = (__bf16*)alloc((size_t)N_ * 256 * sizeof(__bf16));
    float*  ob      = (float*) alloc((size_t)N_ * HID * sizeof(float));
    __bf16* Whi     = (__bf16*)alloc((size_t)4 * 16384 * sizeof(__bf16));
    __bf16* Wlo     = (__bf16*)alloc((size_t)4 * 16384 * sizeof(__bf16));
    float*  bias384 = (float*) alloc(384 * sizeof(float));
    (void)ws_size;

    prep_kernel<<<256, 256, 0, stream>>>(row, row_ptr, N_, E_,
                                         Wq, Wk, Wv, Wo, bq, bk, bv,
                                         Whi, Wlo, bias384);
    qkv_mfma_kernel<<<(N_ + 63) / 64, 256, 0, stream>>>(h, N_, Whi, Wlo, bias384, qb, kvb);
    edge_attn_kernel<<<(N_ + 3) / 4, 256, 0, stream>>>(row_ptr, col, qb, kvb, ob, N_);
    outproj_mfma_kernel<<<(N_ + 63) / 64, 256, 0, stream>>>(
        ob, N_, Whi + 3 * 16384, Wlo + 3 * 16384, bo, out);
}